// Round 7
// baseline (247.384 us; speedup 1.0000x reference)
//
#include <hip/hip_runtime.h>
#include <hip/hip_bf16.h>
#include <cstdint>
#include <cstddef>

#define GLOBAL_AS __attribute__((address_space(1)))
#define LDS_AS __attribute__((address_space(3)))

typedef short bf16x8 __attribute__((ext_vector_type(8)));
typedef float f32x4 __attribute__((ext_vector_type(4)));

constexpr int Bq = 4, Sq = 2048, Eq = 1024, Hh = 16;
constexpr int M = Bq * Sq;   // 8192
constexpr int K = 1024;
constexpr int N = 3 * Eq;    // 3072

// softmax in exp2 domain: p = 2^(s * 0.125 * log2e - 16); no overflow possible
#define SMSC 0.18033688f
#define SMBIAS (-16.0f)

#if __has_builtin(__builtin_amdgcn_exp2f)
#define EXP2F(x) __builtin_amdgcn_exp2f(x)   // bare v_exp_f32
#else
#define EXP2F(x) exp2f(x)
#endif

// RNE float->bf16 (finite inputs only)
static __device__ __forceinline__ unsigned f2bf(float f) {
    union { float f; unsigned u; } v; v.f = f;
    unsigned r = v.u + 0x7fffu + ((v.u >> 16) & 1u);
    return r >> 16;
}

// packed 2x f32 -> bf16 pair (v_cvt_pk_bf16_f32 on gfx950)
static __device__ __forceinline__ unsigned pk2(float a, float b) {
    union { __hip_bfloat162 h; unsigned u; } c;
    c.h = __float22bfloat162_rn(float2{a, b});
    return c.u;
}

// ---------------- prep: x fp32->bf16 (blocks 0..4095) + W transpose (blocks 4096..4863) ----
__global__ __launch_bounds__(256) void prep(const float* __restrict__ X,
                                            unsigned short* __restrict__ Xb,
                                            const float* __restrict__ W,
                                            unsigned short* __restrict__ Wt) {
    __shared__ unsigned short tile[64 * 72];
    const int t = threadIdx.x;
    const int bx = blockIdx.x;
    if (bx < 4096) {
        size_t i = ((size_t)bx * 256 + t) * 8;
        float4 a = *reinterpret_cast<const float4*>(X + i);
        float4 b = *reinterpret_cast<const float4*>(X + i + 4);
        uint4 o;
        o.x = pk2(a.x, a.y);
        o.y = pk2(a.z, a.w);
        o.z = pk2(b.x, b.y);
        o.w = pk2(b.z, b.w);
        *reinterpret_cast<uint4*>(Xb + i) = o;
        return;
    }
    const int idx = bx - 4096;
    const int n0 = (idx % 48) * 64;
    const int k0 = (idx / 48) * 64;
    #pragma unroll
    for (int p = 0; p < 4; ++p) {
        int c = p * 256 + t;
        int row = c >> 4;
        int c4 = (c & 15) * 4;
        float4 v = *reinterpret_cast<const float4*>(W + (size_t)(k0 + row) * N + n0 + c4);
        *reinterpret_cast<unsigned*>(&tile[row * 72 + c4]) = pk2(v.x, v.y);
        *reinterpret_cast<unsigned*>(&tile[row * 72 + c4 + 2]) = pk2(v.z, v.w);
    }
    __syncthreads();
    #pragma unroll
    for (int p = 0; p < 2; ++p) {
        int c = t + p * 256;
        int n = c & 63;
        int kc = (c >> 6) * 8;
        unsigned v[8];
        #pragma unroll
        for (int j = 0; j < 8; ++j) v[j] = tile[(kc + j) * 72 + n];
        uint4 o;
        o.x = v[0] | (v[1] << 16);
        o.y = v[2] | (v[3] << 16);
        o.z = v[4] | (v[5] << 16);
        o.w = v[6] | (v[7] << 16);
        *reinterpret_cast<uint4*>(Wt + (size_t)(n0 + n) * K + k0 + kc) = o;
    }
}

// ---------------- QKV GEMM; V-columns written transposed straight to Vt ----------------
__global__ __launch_bounds__(256) void gemm_qkv(const unsigned short* __restrict__ A,
                                                const unsigned short* __restrict__ Bt,
                                                unsigned short* __restrict__ C,
                                                unsigned short* __restrict__ Vt) {
    __shared__ unsigned short Alds[128 * 64];
    __shared__ unsigned short Blds[128 * 64];
    const int t = threadIdx.x;
    const int lane = t & 63, w = t >> 6;
    const int wm = w >> 1, wn = w & 1;
    const int m0 = blockIdx.y * 128, n0 = blockIdx.x * 128;
    const int lr = lane & 15, quad = lane >> 4;
    const int sw = lr & 7;

    f32x4 acc[4][4] = {};
    for (int k0 = 0; k0 < K; k0 += 64) {
        #pragma unroll
        for (int p = 0; p < 4; ++p) {
            int c = p * 256 + t;
            int row = c >> 3;
            int lch = (c & 7) ^ (row & 7);
            const unsigned short* ga = A + (size_t)(m0 + row) * K + k0 + lch * 8;
            __builtin_amdgcn_global_load_lds((const GLOBAL_AS unsigned int*)ga,
                                             (LDS_AS unsigned int*)&Alds[c * 8], 16, 0, 0);
            const unsigned short* gb = Bt + (size_t)(n0 + row) * K + k0 + lch * 8;
            __builtin_amdgcn_global_load_lds((const GLOBAL_AS unsigned int*)gb,
                                             (LDS_AS unsigned int*)&Blds[c * 8], 16, 0, 0);
        }
        __syncthreads();
        #pragma unroll
        for (int ks = 0; ks < 2; ++ks) {
            bf16x8 af[4], bfr[4];
            const int pch = ((ks * 4 + quad) ^ sw) << 3;
            #pragma unroll
            for (int mt = 0; mt < 4; ++mt)
                af[mt] = *reinterpret_cast<const bf16x8*>(
                    &Alds[(wm * 64 + mt * 16 + lr) * 64 + pch]);
            #pragma unroll
            for (int nt = 0; nt < 4; ++nt)
                bfr[nt] = *reinterpret_cast<const bf16x8*>(
                    &Blds[(wn * 64 + nt * 16 + lr) * 64 + pch]);
            #pragma unroll
            for (int mt = 0; mt < 4; ++mt)
                #pragma unroll
                for (int nt = 0; nt < 4; ++nt)
                    acc[mt][nt] = __builtin_amdgcn_mfma_f32_16x16x32_bf16(af[mt], bfr[nt],
                                                                          acc[mt][nt], 0, 0, 0);
        }
        __syncthreads();
    }
    if (n0 < 2 * Eq) {
        // Q/K columns -> qkv (row-major)
        #pragma unroll
        for (int mt = 0; mt < 4; ++mt)
            #pragma unroll
            for (int nt = 0; nt < 4; ++nt)
                #pragma unroll
                for (int r = 0; r < 4; ++r) {
                    int row = m0 + wm * 64 + mt * 16 + quad * 4 + r;
                    int col = n0 + wn * 64 + nt * 16 + lr;
                    C[(size_t)row * N + col] = (unsigned short)f2bf(acc[mt][nt][r]);
                }
    } else {
        // V columns -> Vt[b][h][d][s], 4 consecutive s per lane -> 8B packed store
        const int b2 = m0 >> 11;
        const int sbase = (m0 & 2047) + wm * 64;
        #pragma unroll
        for (int mt = 0; mt < 4; ++mt)
            #pragma unroll
            for (int nt = 0; nt < 4; ++nt) {
                int hd = n0 - 2 * Eq + wn * 64 + nt * 16 + lr;      // h*64+d
                size_t rowV = (size_t)(b2 * Hh + (hd >> 6)) * 64 + (hd & 63);
                int s = sbase + mt * 16 + quad * 4;
                uint2 val;
                val.x = f2bf(acc[mt][nt][0]) | (f2bf(acc[mt][nt][1]) << 16);
                val.y = f2bf(acc[mt][nt][2]) | (f2bf(acc[mt][nt][3]) << 16);
                *reinterpret_cast<uint2*>(Vt + rowV * Sq + s) = val;
            }
    }
}

// ---------------- Flash attention: kv-tile 32, dbuf, XCD-balanced tile map ----------------
// 1024 blocks, 26.6 KB LDS, 4 blocks/CU all-resident. Blocks l, l+8, l+16, l+24 land on
// the same CU (round-robin XCD dispatch, sequential fill within XCD); tier=(l>>3)&3 with
// i-quadruple {15-g, 8+g, 7-g, g} makes every CU's resident work sum constant (136 iters).
__global__ __launch_bounds__(256, 4) void flash_attn(const unsigned short* __restrict__ QKV,
                                                     const unsigned short* __restrict__ Vt,
                                                     float* __restrict__ Out) {
    __shared__ unsigned short Klds[2][32 * 64];   // [kv32][d64], XOR-swizzled chunks
    __shared__ unsigned short Vlds[2][64 * 32];   // [d64][kv32], natural
    __shared__ unsigned short Plds[4][32 * 40];   // per-wave P, pitch 40 u16
    const int t = threadIdx.x;
    const int lane = t & 63, w = t >> 6;
    const int lr = lane & 15, quad = lane >> 4;

    const int l = blockIdx.x;
    const int tier = (l >> 3) & 3;
    const int unit = ((l >> 5) << 3) | (l & 7);   // [0,256)
    const int g = unit & 3;
    const int hb = unit >> 2;                      // [0,64)
    int i;
    if (tier == 0)      i = 15 - g;
    else if (tier == 1) i = 8 + g;
    else if (tier == 2) i = 7 - g;
    else                i = g;

    const int h = hb & 15, b = hb >> 4;
    const int jmax = 4 * i + 3;                // kv-tiles of 32
    const int jd = 4 * i + w;                  // this wave's diagonal kv-tile
    const int qbase = i * 128 + w * 32;
    unsigned short* Pl = Plds[w];
    const int sw = lr & 7;

    const unsigned short* Kbase = QKV + (size_t)b * Sq * N + Eq + h * 64;
    const unsigned short* Vbase = Vt + (size_t)((b * Hh + h) * 64) * Sq;

    bf16x8 ones;
    #pragma unroll
    for (int z = 0; z < 8; ++z) ones[z] = (short)0x3F80;

    auto stage = [&](int j, int buf) {
        const int kv0 = j * 32;
        {   // K tile: 32 rows x 64 d = 4KB, one 16B op/thread, swizzled
            int row = t >> 3;
            int lch = (t & 7) ^ (row & 7);
            const unsigned short* gk = Kbase + (size_t)(kv0 + row) * N + lch * 8;
            __builtin_amdgcn_global_load_lds((const GLOBAL_AS unsigned int*)gk,
                                             (LDS_AS unsigned int*)&Klds[buf][t * 8], 16, 0, 0);
        }
        {   // V tile: 64 d-rows x 32 kv = 4KB, natural layout
            int row = t >> 2;
            int ch = t & 3;
            const unsigned short* gv = Vbase + (size_t)row * Sq + kv0 + ch * 8;
            __builtin_amdgcn_global_load_lds((const GLOBAL_AS unsigned int*)gv,
                                             (LDS_AS unsigned int*)&Vlds[buf][t * 8], 16, 0, 0);
        }
    };

    // Q A-frags (row = lane&15, k = quad*8+j)
    bf16x8 qf[2][2];
    #pragma unroll
    for (int mt = 0; mt < 2; ++mt)
        #pragma unroll
        for (int ks = 0; ks < 2; ++ks)
            qf[mt][ks] = *reinterpret_cast<const bf16x8*>(
                QKV + (size_t)(b * Sq + qbase + mt * 16 + lr) * N + h * 64 + ks * 32 + quad * 8);

    f32x4 o[2][4] = {};
    f32x4 lsum[2] = {};

    stage(0, 0);
    int cur = 0;
    for (int j = 0; j <= jmax; ++j) {
        __syncthreads();              // buf[cur] staged; prior reads of cur^1 done
        if (j < jmax) stage(j + 1, cur ^ 1);

        if (j <= jd) {                // j > jd: fully masked for this wave
            const unsigned short* Kb = Klds[cur];
            const unsigned short* Vb = Vlds[cur];
            const int kv0 = j * 32;

            // S = Q K^T : 32q x 32kv per wave
            f32x4 sa[2][2] = {};
            #pragma unroll
            for (int ks = 0; ks < 2; ++ks) {
                const int pch = ((ks * 4 + quad) ^ sw) << 3;
                #pragma unroll
                for (int nt = 0; nt < 2; ++nt) {
                    bf16x8 kf = *reinterpret_cast<const bf16x8*>(&Kb[(nt * 16 + lr) * 64 + pch]);
                    #pragma unroll
                    for (int mt = 0; mt < 2; ++mt)
                        sa[mt][nt] = __builtin_amdgcn_mfma_f32_16x16x32_bf16(qf[mt][ks], kf,
                                                                             sa[mt][nt], 0, 0, 0);
                }
            }

            // p = exp2(s*c - 16), truncation bf16 (bias cancels in o/lsum)
            if (j == jd) {
                #pragma unroll
                for (int mt = 0; mt < 2; ++mt)
                    #pragma unroll
                    for (int nt = 0; nt < 2; ++nt)
                        #pragma unroll
                        for (int r = 0; r < 4; ++r) {
                            int qg = qbase + mt * 16 + quad * 4 + r;
                            int kvg = kv0 + nt * 16 + lr;
                            float sc = fmaf(sa[mt][nt][r], SMSC, SMBIAS);
                            sc = (kvg > qg) ? -1e30f : sc;
                            Pl[(mt * 16 + quad * 4 + r) * 40 + nt * 16 + lr] =
                                (unsigned short)(__float_as_uint(EXP2F(sc)) >> 16);
                        }
            } else {
                #pragma unroll
                for (int mt = 0; mt < 2; ++mt)
                    #pragma unroll
                    for (int nt = 0; nt < 2; ++nt)
                        #pragma unroll
                        for (int r = 0; r < 4; ++r)
                            Pl[(mt * 16 + quad * 4 + r) * 40 + nt * 16 + lr] =
                                (unsigned short)(__float_as_uint(
                                    EXP2F(fmaf(sa[mt][nt][r], SMSC, SMBIAS))) >> 16);
            }
            asm volatile("s_waitcnt lgkmcnt(0)" ::: "memory");

            // P A-frags: k = quad*8+jj over 32
            bf16x8 pf[2];
            #pragma unroll
            for (int mt = 0; mt < 2; ++mt)
                pf[mt] = *reinterpret_cast<const bf16x8*>(&Pl[(mt * 16 + lr) * 40 + quad * 8]);

            // O += P V ; lsum += P . 1  (single k=32 contraction)
            #pragma unroll
            for (int dt = 0; dt < 4; ++dt) {
                bf16x8 vf = *reinterpret_cast<const bf16x8*>(&Vb[(dt * 16 + lr) * 32 + quad * 8]);
                #pragma unroll
                for (int mt = 0; mt < 2; ++mt)
                    o[mt][dt] = __builtin_amdgcn_mfma_f32_16x16x32_bf16(pf[mt], vf,
                                                                        o[mt][dt], 0, 0, 0);
            }
            #pragma unroll
            for (int mt = 0; mt < 2; ++mt)
                lsum[mt] = __builtin_amdgcn_mfma_f32_16x16x32_bf16(pf[mt], ones,
                                                                   lsum[mt], 0, 0, 0);
        }
        cur ^= 1;
    }

    // epilogue: out = o / lsum (fp32)
    #pragma unroll
    for (int mt = 0; mt < 2; ++mt)
        #pragma unroll
        for (int r = 0; r < 4; ++r) {
            float inv = 1.0f / lsum[mt][r];
            int qg = qbase + mt * 16 + quad * 4 + r;
            #pragma unroll
            for (int dt = 0; dt < 4; ++dt)
                Out[(size_t)(b * Sq + qg) * Eq + h * 64 + dt * 16 + lr] = o[mt][dt][r] * inv;
        }
}

extern "C" void kernel_launch(void* const* d_in, const int* in_sizes, int n_in,
                              void* d_out, int out_size, void* d_ws, size_t ws_size,
                              hipStream_t stream) {
    const float* x  = (const float*)d_in[0];   // [M][K] fp32
    const float* Wq = (const float*)d_in[1];   // [K][N] fp32
    float* out = (float*)d_out;                // [M][E] fp32

    unsigned short* xb  = (unsigned short*)d_ws;            // M*K bf16
    unsigned short* qkv = xb + (size_t)M * K;               // M*N bf16 (V region unused)
    unsigned short* Wt  = qkv + (size_t)M * N;              // N*K bf16
    unsigned short* Vt  = Wt + (size_t)N * K;               // B*H*D*S bf16

    prep<<<dim3(4096 + 768), 256, 0, stream>>>(x, xb, Wq, Wt);
    gemm_qkv<<<dim3(N / 128, M / 128), 256, 0, stream>>>(xb, Wt, qkv, Vt);
    flash_attn<<<dim3(1024), 256, 0, stream>>>(qkv, Vt, out);
}

// Round 8
// 212.232 us; speedup vs baseline: 1.1656x; 1.1656x over previous
//
#include <hip/hip_runtime.h>
#include <hip/hip_bf16.h>
#include <cstdint>
#include <cstddef>

#define GLOBAL_AS __attribute__((address_space(1)))
#define LDS_AS __attribute__((address_space(3)))

typedef short bf16x8 __attribute__((ext_vector_type(8)));
typedef float f32x4 __attribute__((ext_vector_type(4)));

constexpr int Bq = 4, Sq = 2048, Eq = 1024, Hh = 16;
constexpr int M = Bq * Sq;   // 8192
constexpr int K = 1024;
constexpr int N = 3 * Eq;    // 3072

// softmax in exp2 domain: p = 2^(s * 0.125 * log2e - 16); no overflow possible
#define SMSC 0.18033688f
#define SMBIAS (-16.0f)

#if __has_builtin(__builtin_amdgcn_exp2f)
#define EXP2F(x) __builtin_amdgcn_exp2f(x)   // bare v_exp_f32 (libm exp2f costs ~3x VALU)
#else
#define EXP2F(x) exp2f(x)
#endif

// RNE float->bf16 (finite inputs only)
static __device__ __forceinline__ unsigned f2bf(float f) {
    union { float f; unsigned u; } v; v.f = f;
    unsigned r = v.u + 0x7fffu + ((v.u >> 16) & 1u);
    return r >> 16;
}

// packed 2x f32 -> bf16 pair (v_cvt_pk_bf16_f32 on gfx950)
static __device__ __forceinline__ unsigned pk2(float a, float b) {
    union { __hip_bfloat162 h; unsigned u; } c;
    c.h = __float22bfloat162_rn(float2{a, b});
    return c.u;
}

// ---------------- prep: x fp32->bf16 (blocks 0..4095) + W transpose (blocks 4096..4863) ----
__global__ __launch_bounds__(256) void prep(const float* __restrict__ X,
                                            unsigned short* __restrict__ Xb,
                                            const float* __restrict__ W,
                                            unsigned short* __restrict__ Wt) {
    __shared__ unsigned short tile[64 * 72];
    const int t = threadIdx.x;
    const int bx = blockIdx.x;
    if (bx < 4096) {
        size_t i = ((size_t)bx * 256 + t) * 8;
        float4 a = *reinterpret_cast<const float4*>(X + i);
        float4 b = *reinterpret_cast<const float4*>(X + i + 4);
        uint4 o;
        o.x = pk2(a.x, a.y);
        o.y = pk2(a.z, a.w);
        o.z = pk2(b.x, b.y);
        o.w = pk2(b.z, b.w);
        *reinterpret_cast<uint4*>(Xb + i) = o;
        return;
    }
    const int idx = bx - 4096;
    const int n0 = (idx % 48) * 64;
    const int k0 = (idx / 48) * 64;
    #pragma unroll
    for (int p = 0; p < 4; ++p) {
        int c = p * 256 + t;
        int row = c >> 4;
        int c4 = (c & 15) * 4;
        float4 v = *reinterpret_cast<const float4*>(W + (size_t)(k0 + row) * N + n0 + c4);
        *reinterpret_cast<unsigned*>(&tile[row * 72 + c4]) = pk2(v.x, v.y);
        *reinterpret_cast<unsigned*>(&tile[row * 72 + c4 + 2]) = pk2(v.z, v.w);
    }
    __syncthreads();
    #pragma unroll
    for (int p = 0; p < 2; ++p) {
        int c = t + p * 256;
        int n = c & 63;
        int kc = (c >> 6) * 8;
        unsigned v[8];
        #pragma unroll
        for (int j = 0; j < 8; ++j) v[j] = tile[(kc + j) * 72 + n];
        uint4 o;
        o.x = v[0] | (v[1] << 16);
        o.y = v[2] | (v[3] << 16);
        o.z = v[4] | (v[5] << 16);
        o.w = v[6] | (v[7] << 16);
        *reinterpret_cast<uint4*>(Wt + (size_t)(n0 + n) * K + k0 + kc) = o;
    }
}

// ---------------- QKV GEMM; V-columns written transposed straight to Vt ----------------
__global__ __launch_bounds__(256) void gemm_qkv(const unsigned short* __restrict__ A,
                                                const unsigned short* __restrict__ Bt,
                                                unsigned short* __restrict__ C,
                                                unsigned short* __restrict__ Vt) {
    __shared__ unsigned short Alds[128 * 64];
    __shared__ unsigned short Blds[128 * 64];
    const int t = threadIdx.x;
    const int lane = t & 63, w = t >> 6;
    const int wm = w >> 1, wn = w & 1;
    const int m0 = blockIdx.y * 128, n0 = blockIdx.x * 128;
    const int lr = lane & 15, quad = lane >> 4;
    const int sw = lr & 7;

    f32x4 acc[4][4] = {};
    for (int k0 = 0; k0 < K; k0 += 64) {
        #pragma unroll
        for (int p = 0; p < 4; ++p) {
            int c = p * 256 + t;
            int row = c >> 3;
            int lch = (c & 7) ^ (row & 7);
            const unsigned short* ga = A + (size_t)(m0 + row) * K + k0 + lch * 8;
            __builtin_amdgcn_global_load_lds((const GLOBAL_AS unsigned int*)ga,
                                             (LDS_AS unsigned int*)&Alds[c * 8], 16, 0, 0);
            const unsigned short* gb = Bt + (size_t)(n0 + row) * K + k0 + lch * 8;
            __builtin_amdgcn_global_load_lds((const GLOBAL_AS unsigned int*)gb,
                                             (LDS_AS unsigned int*)&Blds[c * 8], 16, 0, 0);
        }
        __syncthreads();
        #pragma unroll
        for (int ks = 0; ks < 2; ++ks) {
            bf16x8 af[4], bfr[4];
            const int pch = ((ks * 4 + quad) ^ sw) << 3;
            #pragma unroll
            for (int mt = 0; mt < 4; ++mt)
                af[mt] = *reinterpret_cast<const bf16x8*>(
                    &Alds[(wm * 64 + mt * 16 + lr) * 64 + pch]);
            #pragma unroll
            for (int nt = 0; nt < 4; ++nt)
                bfr[nt] = *reinterpret_cast<const bf16x8*>(
                    &Blds[(wn * 64 + nt * 16 + lr) * 64 + pch]);
            #pragma unroll
            for (int mt = 0; mt < 4; ++mt)
                #pragma unroll
                for (int nt = 0; nt < 4; ++nt)
                    acc[mt][nt] = __builtin_amdgcn_mfma_f32_16x16x32_bf16(af[mt], bfr[nt],
                                                                          acc[mt][nt], 0, 0, 0);
        }
        __syncthreads();
    }
    if (n0 < 2 * Eq) {
        // Q/K columns -> qkv (row-major)
        #pragma unroll
        for (int mt = 0; mt < 4; ++mt)
            #pragma unroll
            for (int nt = 0; nt < 4; ++nt)
                #pragma unroll
                for (int r = 0; r < 4; ++r) {
                    int row = m0 + wm * 64 + mt * 16 + quad * 4 + r;
                    int col = n0 + wn * 64 + nt * 16 + lr;
                    C[(size_t)row * N + col] = (unsigned short)f2bf(acc[mt][nt][r]);
                }
    } else {
        // V columns -> Vt[b][h][d][s], 4 consecutive s per lane -> 8B packed store
        const int b2 = m0 >> 11;
        const int sbase = (m0 & 2047) + wm * 64;
        #pragma unroll
        for (int mt = 0; mt < 4; ++mt)
            #pragma unroll
            for (int nt = 0; nt < 4; ++nt) {
                int hd = n0 - 2 * Eq + wn * 64 + nt * 16 + lr;      // h*64+d
                size_t rowV = (size_t)(b2 * Hh + (hd >> 6)) * 64 + (hd & 63);
                int s = sbase + mt * 16 + quad * 4;
                uint2 val;
                val.x = f2bf(acc[mt][nt][0]) | (f2bf(acc[mt][nt][1]) << 16);
                val.y = f2bf(acc[mt][nt][2]) | (f2bf(acc[mt][nt][3]) << 16);
                *reinterpret_cast<uint2*>(Vt + rowV * Sq + s) = val;
            }
    }
}

// ---------------- Flash attention: kv-tile 32, dbuf, all blocks resident ----------------
// grid (64 hb, 16 tiles): linear id = hb + 64*y, 64%8==0 -> all 16 tiles of a head land on
// XCD hb%8; per-XCD L2 holds exactly its 8 heads' K/V (8 x 512 KB = 4 MB). Do NOT remap
// blocks across hb (round 7: +2.7x HBM fetch). LDS 26.6 KB -> 4 blocks/CU, grid resident.
__global__ __launch_bounds__(256, 4) void flash_attn(const unsigned short* __restrict__ QKV,
                                                     const unsigned short* __restrict__ Vt,
                                                     float* __restrict__ Out) {
    __shared__ unsigned short Klds[2][32 * 64];   // [kv32][d64], XOR-swizzled chunks
    __shared__ unsigned short Vlds[2][64 * 32];   // [d64][kv32], natural
    __shared__ unsigned short Plds[4][32 * 40];   // per-wave P, pitch 40 u16
    const int t = threadIdx.x;
    const int lane = t & 63, w = t >> 6;
    const int lr = lane & 15, quad = lane >> 4;
    const int hb = blockIdx.x;
    const int h = hb & 15, b = hb >> 4;
    const int i = 15 - (int)blockIdx.y;        // big q-tiles first
    const int jmax = 4 * i + 3;                // kv-tiles of 32
    const int jd = 4 * i + w;                  // this wave's diagonal kv-tile
    const int qbase = i * 128 + w * 32;
    unsigned short* Pl = Plds[w];
    const int sw = lr & 7;

    const unsigned short* Kbase = QKV + (size_t)b * Sq * N + Eq + h * 64;
    const unsigned short* Vbase = Vt + (size_t)((b * Hh + h) * 64) * Sq;

    bf16x8 ones;
    #pragma unroll
    for (int z = 0; z < 8; ++z) ones[z] = (short)0x3F80;

    auto stage = [&](int j, int buf) {
        const int kv0 = j * 32;
        {   // K tile: 32 rows x 64 d = 4KB, one 16B op/thread, swizzled
            int row = t >> 3;
            int lch = (t & 7) ^ (row & 7);
            const unsigned short* gk = Kbase + (size_t)(kv0 + row) * N + lch * 8;
            __builtin_amdgcn_global_load_lds((const GLOBAL_AS unsigned int*)gk,
                                             (LDS_AS unsigned int*)&Klds[buf][t * 8], 16, 0, 0);
        }
        {   // V tile: 64 d-rows x 32 kv = 4KB, natural layout
            int row = t >> 2;
            int ch = t & 3;
            const unsigned short* gv = Vbase + (size_t)row * Sq + kv0 + ch * 8;
            __builtin_amdgcn_global_load_lds((const GLOBAL_AS unsigned int*)gv,
                                             (LDS_AS unsigned int*)&Vlds[buf][t * 8], 16, 0, 0);
        }
    };

    // Q A-frags (row = lane&15, k = quad*8+j)
    bf16x8 qf[2][2];
    #pragma unroll
    for (int mt = 0; mt < 2; ++mt)
        #pragma unroll
        for (int ks = 0; ks < 2; ++ks)
            qf[mt][ks] = *reinterpret_cast<const bf16x8*>(
                QKV + (size_t)(b * Sq + qbase + mt * 16 + lr) * N + h * 64 + ks * 32 + quad * 8);

    f32x4 o[2][4] = {};
    f32x4 lsum[2] = {};

    stage(0, 0);
    int cur = 0;
    for (int j = 0; j <= jmax; ++j) {
        __syncthreads();              // buf[cur] staged; prior reads of cur^1 done
        if (j < jmax) stage(j + 1, cur ^ 1);

        if (j <= jd) {                // j > jd: fully masked for this wave
            const unsigned short* Kb = Klds[cur];
            const unsigned short* Vb = Vlds[cur];
            const int kv0 = j * 32;

            // S = Q K^T : 32q x 32kv per wave
            f32x4 sa[2][2] = {};
            #pragma unroll
            for (int ks = 0; ks < 2; ++ks) {
                const int pch = ((ks * 4 + quad) ^ sw) << 3;
                #pragma unroll
                for (int nt = 0; nt < 2; ++nt) {
                    bf16x8 kf = *reinterpret_cast<const bf16x8*>(&Kb[(nt * 16 + lr) * 64 + pch]);
                    #pragma unroll
                    for (int mt = 0; mt < 2; ++mt)
                        sa[mt][nt] = __builtin_amdgcn_mfma_f32_16x16x32_bf16(qf[mt][ks], kf,
                                                                             sa[mt][nt], 0, 0, 0);
                }
            }

            // p = exp2(s*c - 16), truncation bf16 (bias cancels in o/lsum)
            if (j == jd) {
                #pragma unroll
                for (int mt = 0; mt < 2; ++mt)
                    #pragma unroll
                    for (int nt = 0; nt < 2; ++nt)
                        #pragma unroll
                        for (int r = 0; r < 4; ++r) {
                            int qg = qbase + mt * 16 + quad * 4 + r;
                            int kvg = kv0 + nt * 16 + lr;
                            float sc = fmaf(sa[mt][nt][r], SMSC, SMBIAS);
                            sc = (kvg > qg) ? -1e30f : sc;
                            Pl[(mt * 16 + quad * 4 + r) * 40 + nt * 16 + lr] =
                                (unsigned short)(__float_as_uint(EXP2F(sc)) >> 16);
                        }
            } else {
                #pragma unroll
                for (int mt = 0; mt < 2; ++mt)
                    #pragma unroll
                    for (int nt = 0; nt < 2; ++nt)
                        #pragma unroll
                        for (int r = 0; r < 4; ++r)
                            Pl[(mt * 16 + quad * 4 + r) * 40 + nt * 16 + lr] =
                                (unsigned short)(__float_as_uint(
                                    EXP2F(fmaf(sa[mt][nt][r], SMSC, SMBIAS))) >> 16);
            }
            asm volatile("s_waitcnt lgkmcnt(0)" ::: "memory");

            // P A-frags: k = quad*8+jj over 32
            bf16x8 pf[2];
            #pragma unroll
            for (int mt = 0; mt < 2; ++mt)
                pf[mt] = *reinterpret_cast<const bf16x8*>(&Pl[(mt * 16 + lr) * 40 + quad * 8]);

            // O += P V ; lsum += P . 1  (single k=32 contraction)
            #pragma unroll
            for (int dt = 0; dt < 4; ++dt) {
                bf16x8 vf = *reinterpret_cast<const bf16x8*>(&Vb[(dt * 16 + lr) * 32 + quad * 8]);
                #pragma unroll
                for (int mt = 0; mt < 2; ++mt)
                    o[mt][dt] = __builtin_amdgcn_mfma_f32_16x16x32_bf16(pf[mt], vf,
                                                                        o[mt][dt], 0, 0, 0);
            }
            #pragma unroll
            for (int mt = 0; mt < 2; ++mt)
                lsum[mt] = __builtin_amdgcn_mfma_f32_16x16x32_bf16(pf[mt], ones,
                                                                   lsum[mt], 0, 0, 0);
        }
        cur ^= 1;
    }

    // epilogue: out = o / lsum (fp32)
    #pragma unroll
    for (int mt = 0; mt < 2; ++mt)
        #pragma unroll
        for (int r = 0; r < 4; ++r) {
            float inv = 1.0f / lsum[mt][r];
            int qg = qbase + mt * 16 + quad * 4 + r;
            #pragma unroll
            for (int dt = 0; dt < 4; ++dt)
                Out[(size_t)(b * Sq + qg) * Eq + h * 64 + dt * 16 + lr] = o[mt][dt][r] * inv;
        }
}

extern "C" void kernel_launch(void* const* d_in, const int* in_sizes, int n_in,
                              void* d_out, int out_size, void* d_ws, size_t ws_size,
                              hipStream_t stream) {
    const float* x  = (const float*)d_in[0];   // [M][K] fp32
    const float* Wq = (const float*)d_in[1];   // [K][N] fp32
    float* out = (float*)d_out;                // [M][E] fp32

    unsigned short* xb  = (unsigned short*)d_ws;            // M*K bf16
    unsigned short* qkv = xb + (size_t)M * K;               // M*N bf16 (V region unused)
    unsigned short* Wt  = qkv + (size_t)M * N;              // N*K bf16
    unsigned short* Vt  = Wt + (size_t)N * K;               // B*H*D*S bf16

    prep<<<dim3(4096 + 768), 256, 0, stream>>>(x, xb, Wq, Wt);
    gemm_qkv<<<dim3(N / 128, M / 128), 256, 0, stream>>>(xb, Wt, qkv, Vt);
    flash_attn<<<dim3(Hh * Bq, 16), 256, 0, stream>>>(qkv, Vt, out);
}